// Round 21
// baseline (292.516 us; speedup 1.0000x reference)
//
#include <hip/hip_runtime.h>
#include <stdint.h>

// ---------------------------------------------------------------------------
// GraphAttentionLayer fused pipeline, MI355X (gfx950)
// B=64 S=512 C=512 H=4 D=128.  Split-bf16 (hi+lo) MFMA: proj 3-term,
// attn QK^T 2-term (kh*qh + kh*ql; K-residual dropped -> K_lo never staged).
// Round 21: attn LDS halves (16KB/buffer) -> 48KB pad -> 3 blocks/CU;
// QK^T MFMA -33%; K HBM stream halved; setprio removed (measured null).
// proj (BK=64 counted-vmcnt, r20) / ln / casts frozen.
// ---------------------------------------------------------------------------

typedef float  f32x4   __attribute__((ext_vector_type(4)));
typedef short  bf16x8  __attribute__((ext_vector_type(8)));
typedef unsigned short ushort8 __attribute__((ext_vector_type(8)));
typedef unsigned int   uint2v  __attribute__((ext_vector_type(2)));
typedef unsigned int   uint4v  __attribute__((ext_vector_type(4)));

#define GLD16(src, dst)                                                        \
  __builtin_amdgcn_global_load_lds(                                            \
      (const __attribute__((address_space(1))) void*)(src),                    \
      (__attribute__((address_space(3))) void*)(dst), 16, 0, 0)

__device__ __forceinline__ unsigned short f32_to_bf16(float x) {
  union { float f; unsigned int u; } v; v.f = x;
  unsigned int r = v.u + 0x7FFFu + ((v.u >> 16) & 1u);
  return (unsigned short)(r >> 16);
}
__device__ __forceinline__ float bf16_to_f32(unsigned int h) {
  union { float f; unsigned int u; } v; v.u = h << 16;
  return v.f;
}
__device__ __forceinline__ f32x4 mfma16(bf16x8 a, bf16x8 b, f32x4 c) {
  return __builtin_amdgcn_mfma_f32_16x16x32_bf16(a, b, c, 0, 0, 0);
}
__device__ __forceinline__ float bperm_f(int srcLane, float v) {
  return __int_as_float(__builtin_amdgcn_ds_bpermute(srcLane << 2, __float_as_int(v)));
}
// Trunc-split pair pack: two f32 -> {hi 2xbf16, lo 2xbf16} as uint2.
__device__ __forceinline__ uint2 pk2(float fa, float fb) {
  unsigned ua = __float_as_uint(fa), ub = __float_as_uint(fb);
  uint2 r;
  r.x = (ua >> 16) | (ub & 0xFFFF0000u);
  float ra = fa - __uint_as_float(ua & 0xFFFF0000u);
  float rb = fb - __uint_as_float(ub & 0xFFFF0000u);
  r.y = (__float_as_uint(ra) >> 16) | (__float_as_uint(rb) & 0xFFFF0000u);
  return r;
}
// HW transpose read, canonical per-lane b64 address (base + lane*8B).
__device__ __forceinline__ uint2v tr_read(const unsigned short* p) {
  uint2v r;
  asm volatile("ds_read_b64_tr_b16 %0, %1"
               : "=v"(r)
               : "v"((const __attribute__((address_space(3))) void*)p)
               : "memory");
  return r;
}

// ---------------------------------------------------------------------------
// Kernel 2: W [H,C,D] fp32 -> Wt_hi/lo [H,D,C] bf16 (transposed per head).
// ---------------------------------------------------------------------------
__global__ __launch_bounds__(256) void cast_split_Wt(
    const float* __restrict__ W, unsigned short* __restrict__ whi,
    unsigned short* __restrict__ wlo) {
  int o = blockIdx.x * 256 + threadIdx.x;      // [0, 4*128*512)
  int hd = o >> 16;                             // head
  int rem = o & 65535;
  int d = rem >> 9;                             // [0,128)
  int c = rem & 511;                            // [0,512)
  float v = W[((size_t)(hd * 512 + c)) * 128 + d];
  unsigned short h0 = f32_to_bf16(v);
  whi[o] = h0;
  wlo[o] = f32_to_bf16(v - bf16_to_f32(h0));
}

// ---------------------------------------------------------------------------
// Kernel 2b: adj (fp32) -> bf16 (exact for 0/1 masks).  8 elems/thread.
// ---------------------------------------------------------------------------
__global__ __launch_bounds__(256) void cast_adj(
    const float* __restrict__ src, unsigned short* __restrict__ dst) {
  size_t i = ((size_t)blockIdx.x * 256 + threadIdx.x) * 8;
  f32x4 a = *(const f32x4*)(src + i);
  f32x4 b = *(const f32x4*)(src + i + 4);
  ushort8 o;
#pragma unroll
  for (int e = 0; e < 4; ++e) {
    o[e] = f32_to_bf16(a[e]);
    o[4 + e] = f32_to_bf16(b[e]);
  }
  *(ushort8*)(dst + i) = o;
}

// ---------------------------------------------------------------------------
// Kernel 3: FUSED cast+projection GEMM  hp = split(h) @ Wall + bias.
// BK=64 (r20, unchanged): 8 K-steps, canonical (row&7)<<4 swizzle, B via
// GLD16, A reg-staged + prefetch, counted vmcnt(8) drain.
// ---------------------------------------------------------------------------
__global__ __launch_bounds__(256, 2) void proj_gemm(
    const float* __restrict__ hsrc,
    const unsigned short* __restrict__ whi, const unsigned short* __restrict__ wlo,
    const float* __restrict__ bias, unsigned short* __restrict__ hp_hi,
    unsigned short* __restrict__ hp_lo) {
  int bid = blockIdx.x;
  int swz = (bid & 7) * 128 + (bid >> 3);       // XCD-contiguous work chunks
  int nt = swz & 3, mt = swz >> 2;
  int m0 = mt * 128, n0 = nt * 128;             // n-tile == head nt

  __shared__ alignas(16) unsigned short Ah[8192], Al[8192], Bh[8192], Bl[8192];

  int tid = threadIdx.x, wv = tid >> 6, lane = tid & 63;
  int l15 = lane & 15, l4 = lane >> 4;
  int wr = wv >> 1, wc = wv & 1;
  int arow = tid >> 3;                          // 0..31
  int acol8 = (tid & 7) * 8;                    // f32 col base (8 per thread)

  f32x4 acc[4][4];
#pragma unroll
  for (int a = 0; a < 4; ++a)
#pragma unroll
    for (int b = 0; b < 4; ++b) acc[a][b] = (f32x4){0.f, 0.f, 0.f, 0.f};

  // ---- prologue: A[0] into regs (8 x f32x4)
  f32x4 areg[4][2];
#pragma unroll
  for (int j = 0; j < 4; ++j) {
    const float* rp = hsrc + (size_t)(m0 + j * 32 + arow) * 512 + acol8;
    areg[j][0] = *(const f32x4*)rp;
    areg[j][1] = *(const f32x4*)(rp + 4);
  }

  for (int ks = 0; ks < 8; ++ks) {
    int k0 = ks * 64;
    // 1) B staging via GLD16: 32 x 1KB chunks over 4 waves (oldest vm ops)
    for (int i = wv; i < 32; i += 4) {
      int grp = i >> 4, j = i & 15;
      int row = j * 8 + (lane >> 3);
      int off = (lane & 7) * 16;
      int sw = (row & 7) << 4;
      const unsigned short* sb = grp ? wlo : whi;
      unsigned short* db = grp ? Bl : Bh;
      GLD16((const char*)sb + ((size_t)(nt * 128 + row) * 512 + k0) * 2 + (off ^ sw),
            db + j * 512);
    }
    __builtin_amdgcn_sched_barrier(0);          // pin GLD16s as oldest
    // 2) split A[ks] regs -> swizzled ds_write_b128 (hi + lo)
#pragma unroll
    for (int j = 0; j < 4; ++j) {
      int r = j * 32 + arow;
      uint4v uh, ul;
      uint2 p0 = pk2(areg[j][0][0], areg[j][0][1]);
      uint2 p1 = pk2(areg[j][0][2], areg[j][0][3]);
      uint2 p2 = pk2(areg[j][1][0], areg[j][1][1]);
      uint2 p3 = pk2(areg[j][1][2], areg[j][1][3]);
      uh[0] = p0.x; ul[0] = p0.y;
      uh[1] = p1.x; ul[1] = p1.y;
      uh[2] = p2.x; ul[2] = p2.y;
      uh[3] = p3.x; ul[3] = p3.y;
      int boff = r * 128 + ((acol8 * 2) ^ ((r & 7) << 4));
      *(uint4v*)((char*)Ah + boff) = uh;
      *(uint4v*)((char*)Al + boff) = ul;
    }
    // 3) A[ks+1] prefetch (youngest vm ops, stay in flight across barrier)
    if (ks < 7) {
#pragma unroll
      for (int j = 0; j < 4; ++j) {
        const float* rp = hsrc + (size_t)(m0 + j * 32 + arow) * 512 + k0 + 64 + acol8;
        areg[j][0] = *(const f32x4*)rp;
        areg[j][1] = *(const f32x4*)(rp + 4);
      }
    }
    // 4) counted drain: B + ds_writes done; A-prefetch (8 loads) keeps flying
    if (ks < 7) {
      asm volatile("s_waitcnt vmcnt(8) lgkmcnt(0)" ::: "memory");
    } else {
      asm volatile("s_waitcnt vmcnt(0) lgkmcnt(0)" ::: "memory");
    }
    __builtin_amdgcn_s_barrier();
    __builtin_amdgcn_sched_barrier(0);

    // 5) MFMA over the 2 k-halves of the 64-wide tile
#pragma unroll
    for (int ks2 = 0; ks2 < 2; ++ks2) {
      int kb = (ks2 * 64 + 16 * l4);
      bf16x8 fah[4], fal[4], fbh[4], fbl[4];
#pragma unroll
      for (int f = 0; f < 4; ++f) {
        int mr = wr * 64 + f * 16 + l15;
        int aadr = mr * 128 + (kb ^ ((mr & 7) << 4));
        fah[f] = *(const bf16x8*)((const char*)Ah + aadr);
        fal[f] = *(const bf16x8*)((const char*)Al + aadr);
        int nr = wc * 64 + f * 16 + l15;
        int badr = nr * 128 + (kb ^ ((nr & 7) << 4));
        fbh[f] = *(const bf16x8*)((const char*)Bh + badr);
        fbl[f] = *(const bf16x8*)((const char*)Bl + badr);
      }
#pragma unroll
      for (int a = 0; a < 4; ++a)
#pragma unroll
        for (int b = 0; b < 4; ++b) {
          acc[a][b] = mfma16(fah[a], fbh[b], acc[a][b]);
          acc[a][b] = mfma16(fah[a], fbl[b], acc[a][b]);
          acc[a][b] = mfma16(fal[a], fbh[b], acc[a][b]);
        }
    }
    // 6) WAR fence (own LDS reads done); do NOT drain vmcnt mid-loop
    asm volatile("s_waitcnt lgkmcnt(0)" ::: "memory");
    __builtin_amdgcn_s_barrier();
    __builtin_amdgcn_sched_barrier(0);
  }

  __syncthreads();   // full drain before epilogue reuses Ah/Al

  // epilogue: +bias, RNE split, LDS-staged coalesced writes of hp rows.
#pragma unroll
  for (int a = 0; a < 4; ++a) {
    __syncthreads();
#pragma unroll
    for (int b = 0; b < 4; ++b) {
      int cloc = wc * 64 + b * 16 + l15;
      float bv = bias[n0 + cloc];
#pragma unroll
      for (int r = 0; r < 4; ++r) {
        int rloc = wr * 16 + 4 * l4 + r;
        float v = acc[a][b][r] + bv;
        unsigned short hh = f32_to_bf16(v);
        Ah[rloc * 128 + cloc] = hh;
        Al[rloc * 128 + cloc] = f32_to_bf16(v - bf16_to_f32(hh));
      }
    }
    __syncthreads();
    int rr = tid >> 3, c16 = (tid & 7) * 16;
    int mg = m0 + (rr >> 4) * 64 + a * 16 + (rr & 15);
    bf16x8 vh0 = *(const bf16x8*)(Ah + rr * 128 + c16);
    bf16x8 vh1 = *(const bf16x8*)(Ah + rr * 128 + c16 + 8);
    bf16x8 vl0 = *(const bf16x8*)(Al + rr * 128 + c16);
    bf16x8 vl1 = *(const bf16x8*)(Al + rr * 128 + c16 + 8);
    *(bf16x8*)(hp_hi + (size_t)mg * 512 + n0 + c16) = vh0;
    *(bf16x8*)(hp_hi + (size_t)mg * 512 + n0 + c16 + 8) = vh1;
    *(bf16x8*)(hp_lo + (size_t)mg * 512 + n0 + c16) = vl0;
    *(bf16x8*)(hp_lo + (size_t)mg * 512 + n0 + c16 + 8) = vl1;
  }
}

// ---------------------------------------------------------------------------
// Kernel 5: flash attention, q-tile 128, kv-tile 64.  4 waves x 32 q (nf).
// QK^T 2-term (kh*qh + kh*ql): K_lo never staged.  K_hi only, subtiled
// [2 kvh][8 sd][32 kv][16 d], double-buffered (2 x 16KB).  PV single-term
// trunc-bf16(P)@V_hi via tr_read.  8 iters, 1 barrier each, hardened drains.
// 48KB LDS pad -> 3 blocks/CU.  bf16 adj in, bf16 out.
// ---------------------------------------------------------------------------
__global__ __launch_bounds__(256, 3) void attn_kernel(
    const unsigned short* __restrict__ hp_hi, const unsigned short* __restrict__ hp_lo,
    const unsigned short* __restrict__ adjb, unsigned short* __restrict__ ob) {
  int bid = blockIdx.x;
  int swz = (bid & 7) * 128 + (bid >> 3);       // 4 q-tiles of one (b,h) per XCD
  int qt = swz & 3;
  int hd = (swz >> 2) & 3;
  int bb = swz >> 4;
  int q0 = qt * 128;

  __shared__ alignas(16) unsigned short SM[24576];     // 48 KB -> 3 blocks/CU
  // buf0 @0, buf1 @8192 (u16).  Buffer = [2 kvh][8 sd] x 512 u16 subtiles.

  int tid = threadIdx.x, w = tid >> 6, lane = tid & 63;
  int l15 = lane & 15, l4 = lane >> 4;
  int qgb = q0 + w * 32 + l15;                  // + nf*16 for the softmax row

  // Q fragments (B-operand: n=q at l&15, k=d contiguous), hi+lo, 2 nf sets
  bf16x8 qh[2][4], ql[2][4];
#pragma unroll
  for (int nf = 0; nf < 2; ++nf) {
    size_t base = ((size_t)bb * 512 + qgb + nf * 16) * 512 + hd * 128 + 8 * l4;
#pragma unroll
    for (int ds = 0; ds < 4; ++ds) {
      qh[nf][ds] = *(const bf16x8*)(hp_hi + base + ds * 32);
      ql[nf][ds] = *(const bf16x8*)(hp_lo + base + ds * 32);
    }
  }

  f32x4 o[2][8];
#pragma unroll
  for (int nf = 0; nf < 2; ++nf)
#pragma unroll
    for (int vf = 0; vf < 8; ++vf) o[nf][vf] = (f32x4){0.f, 0.f, 0.f, 0.f};
  float m_run[2] = {-3.0e38f, -3.0e38f};
  float l_run[2] = {0.f, 0.f};

  // staging: wave w owns subtiles s = w*4 .. w*4+3 of [kvh(2)][sd(8)]
  int skv = lane >> 1, sdh = lane & 1;

  // ---- prologue: stage K_hi[0..63] into buf0
#pragma unroll
  for (int j = 0; j < 4; ++j) {
    int s = w * 4 + j;
    int kvh = s >> 3, sd = s & 7;
    const char* src = (const char*)hp_hi +
        ((size_t)(bb * 512 + kvh * 32 + skv)) * 1024 + hd * 256 + sd * 32 + sdh * 16;
    GLD16(src, SM + kvh * 4096 + sd * 512);
  }
  asm volatile("s_waitcnt vmcnt(0)" ::: "memory");
  __syncthreads();

  for (int t = 0; t < 8; ++t) {
    int kv0 = t * 64;
    const unsigned short* Kb = SM + ((t & 1) << 13);

    // ---- stage next 64-kv tile (K_hi only) into the other buffer
    if (t < 7) {
      unsigned short* Nb = SM + (((t + 1) & 1) << 13);
#pragma unroll
      for (int j = 0; j < 4; ++j) {
        int s = w * 4 + j;
        int kvh = s >> 3, sd = s & 7;
        const char* src = (const char*)hp_hi +
            ((size_t)(bb * 512 + kv0 + 64 + kvh * 32 + skv)) * 1024 +
            hd * 256 + sd * 32 + sdh * 16;
        GLD16(src, Nb + kvh * 4096 + sd * 512);
      }
    }
    // adj loads early (bf16): group m covers kv = m*16 + 4*l4 + r
    uint2 ua[2][4];
#pragma unroll
    for (int nf = 0; nf < 2; ++nf) {
      const unsigned short* ab = adjb + (size_t)(qgb + nf * 16) * 512 + kv0;
#pragma unroll
      for (int m = 0; m < 4; ++m)
        ua[nf][m] = *(const uint2*)(ab + m * 16 + 4 * l4);
    }

    // ---- QK^T (swapped, 2-term): K_hi frags read once, serve both nf
    f32x4 sc[2][4];
#pragma unroll
    for (int nf = 0; nf < 2; ++nf)
#pragma unroll
      for (int m = 0; m < 4; ++m) sc[nf][m] = (f32x4){0.f, 0.f, 0.f, 0.f};
#pragma unroll
    for (int kvh = 0; kvh < 2; ++kvh) {
#pragma unroll
      for (int ds = 0; ds < 4; ++ds) {
        int boff = (kvh * 8 + 2 * ds + (l4 >> 1)) * 1024 + 16 * (l4 & 1);
        int a0 = boff + l15 * 32;
        int a1 = boff + (16 + l15) * 32;
        bf16x8 kh0 = *(const bf16x8*)((const char*)Kb + a0);
        bf16x8 kh1 = *(const bf16x8*)((const char*)Kb + a1);
        int m0i = kvh * 2, m1i = kvh * 2 + 1;
#pragma unroll
        for (int nf = 0; nf < 2; ++nf) {
          sc[nf][m0i] = mfma16(kh0, qh[nf][ds], sc[nf][m0i]);
          sc[nf][m1i] = mfma16(kh1, qh[nf][ds], sc[nf][m1i]);
          sc[nf][m0i] = mfma16(kh0, ql[nf][ds], sc[nf][m0i]);
          sc[nf][m1i] = mfma16(kh1, ql[nf][ds], sc[nf][m1i]);
        }
      }
    }

    // ---- adj multiply + online softmax + pack, per nf
    union PU { bf16x8 v; unsigned u[4]; } pah[2][2];  // [nf][kvh]
#pragma unroll
    for (int nf = 0; nf < 2; ++nf) {
      float p[4][4];
      float tm = -3.0e38f;
#pragma unroll
      for (int m = 0; m < 4; ++m) {
        f32x4 av;
        av[0] = bf16_to_f32(ua[nf][m].x & 0xFFFFu);
        av[1] = bf16_to_f32(ua[nf][m].x >> 16);
        av[2] = bf16_to_f32(ua[nf][m].y & 0xFFFFu);
        av[3] = bf16_to_f32(ua[nf][m].y >> 16);
#pragma unroll
        for (int r = 0; r < 4; ++r) {
          p[m][r] = sc[nf][m][r] * av[r];
          tm = fmaxf(tm, p[m][r]);
        }
      }
      tm = fmaxf(tm, __shfl_xor(tm, 16));
      tm = fmaxf(tm, __shfl_xor(tm, 32));
      if (__any(tm > m_run[nf] + 8.0f)) {       // T13 defer-rescale
        float mn = fmaxf(m_run[nf], tm);
        float scl = __expf(m_run[nf] - mn);
        m_run[nf] = mn;
        l_run[nf] *= scl;
        f32x4 s4;
#pragma unroll
        for (int r = 0; r < 4; ++r) s4[r] = bperm_f(4 * l4 + r, scl);
#pragma unroll
        for (int vf = 0; vf < 8; ++vf)
#pragma unroll
          for (int r = 0; r < 4; ++r) o[nf][vf][r] *= s4[r];
      }
      float ps = 0.f;
#pragma unroll
      for (int m = 0; m < 4; ++m)
#pragma unroll
        for (int r = 0; r < 4; ++r) {
          p[m][r] = __expf(p[m][r] - m_run[nf]);
          ps += p[m][r];
        }
      ps += __shfl_xor(ps, 16);
      ps += __shfl_xor(ps, 32);
      l_run[nf] += ps;
#pragma unroll
      for (int kvh = 0; kvh < 2; ++kvh)
#pragma unroll
        for (int i = 0; i < 4; ++i) {
          float fa = (i < 2) ? p[kvh * 2][2 * i] : p[kvh * 2 + 1][2 * (i - 2)];
          float fb = (i < 2) ? p[kvh * 2][2 * i + 1]
                             : p[kvh * 2 + 1][2 * (i - 2) + 1];
          pah[nf][kvh].u[i] = (__float_as_uint(fa) >> 16) |
                              (__float_as_uint(fb) & 0xFFFF0000u);
        }
    }

    // ---- O += P @ V_hi per kvh: tr_read 16, lgkm drain, 16 MFMA
#pragma unroll
    for (int kvh = 0; kvh < 2; ++kvh) {
      const unsigned short* trb = Kb + kvh * 4096 + lane * 4;
      union VU { bf16x8 v; uint2v u2[2]; } vh[8];
#pragma unroll
      for (int vf = 0; vf < 8; ++vf) {
        vh[vf].u2[0] = tr_read(trb + vf * 512);
        vh[vf].u2[1] = tr_read(trb + vf * 512 + 256);
      }
      asm volatile("s_waitcnt lgkmcnt(0)" ::: "memory");
      __builtin_amdgcn_sched_barrier(0);
#pragma unroll
      for (int vf = 0; vf < 8; ++vf) {
        o[0][vf] = mfma16(pah[0][kvh].v, vh[vf].v, o[0][vf]);
        o[1][vf] = mfma16(pah[1][kvh].v, vh[vf].v, o[1][vf]);
      }
    }
    asm volatile("s_waitcnt vmcnt(0) lgkmcnt(0)" ::: "memory");
    __syncthreads();   // next tile staged+visible; WAR turnover on buf[t&1]
  }

  // ---- epilogue: 2 passes (nf), wave-private LDS chunk, coalesced bf16 out
#pragma unroll
  for (int nf = 0; nf < 2; ++nf) {
    float rinv = 1.0f / l_run[nf];
    f32x4 r4;
#pragma unroll
    for (int r = 0; r < 4; ++r) r4[r] = bperm_f(4 * l4 + r, rinv);
    float* wbase = (float*)SM + w * 2048;       // [16][128] f32 per wave
#pragma unroll
    for (int vf = 0; vf < 8; ++vf)
#pragma unroll
      for (int r = 0; r < 4; ++r)
        wbase[(4 * l4 + r) * 128 + vf * 16 + l15] = o[nf][vf][r] * r4[r];
    __syncthreads();
#pragma unroll
    for (int p = 0; p < 4; ++p) {
      int row = p * 4 + l4;
      f32x4 v0 = *(const f32x4*)(wbase + row * 128 + l15 * 8);
      f32x4 v1 = *(const f32x4*)(wbase + row * 128 + l15 * 8 + 4);
      ushort8 o8;
#pragma unroll
      for (int e = 0; e < 4; ++e) {
        o8[e] = f32_to_bf16(v0[e]);
        o8[4 + e] = f32_to_bf16(v1[e]);
      }
      size_t mg = (size_t)bb * 512 + q0 + w * 32 + nf * 16 + row;
      *(ushort8*)(ob + mg * 512 + hd * 128 + l15 * 8) = o8;
    }
    __syncthreads();
  }
}

// ---------------------------------------------------------------------------
// Kernel 6: LayerNorm (over C=512) + exact-erf GELU.  bf16 in, fp32 out.
// ---------------------------------------------------------------------------
__global__ __launch_bounds__(256) void ln_gelu_kernel(
    const unsigned short* __restrict__ in, float* __restrict__ outp,
    const float* __restrict__ gamma, const float* __restrict__ beta) {
  int w = threadIdx.x >> 6, lane = threadIdx.x & 63;
  size_t row = (size_t)blockIdx.x * 4 + w;
  ushort8 v = *(const ushort8*)(in + row * 512 + lane * 8);
  float x[8];
#pragma unroll
  for (int e = 0; e < 8; ++e) x[e] = bf16_to_f32((unsigned int)(unsigned short)v[e]);
  float s = 0.f;
#pragma unroll
  for (int e = 0; e < 8; ++e) s += x[e];
#pragma unroll
  for (int off = 32; off >= 1; off >>= 1) s += __shfl_xor(s, off);
  float mu = s * (1.0f / 512.0f);
  float vs = 0.f;
#pragma unroll
  for (int e = 0; e < 8; ++e) {
    float d = x[e] - mu; vs += d * d;
  }
#pragma unroll
  for (int off = 32; off >= 1; off >>= 1) vs += __shfl_xor(vs, off);
  float rs = rsqrtf(vs * (1.0f / 512.0f) + 1e-5f);
  f32x4 g0 = *(const f32x4*)(gamma + lane * 8);
  f32x4 g1 = *(const f32x4*)(gamma + lane * 8 + 4);
  f32x4 b0 = *(const f32x4*)(beta + lane * 8);
  f32x4 b1 = *(const f32x4*)(beta + lane * 8 + 4);
  f32x4 y0, y1;
#pragma unroll
  for (int e = 0; e < 4; ++e) {
    float y = (x[e] - mu) * rs * g0[e] + b0[e];
    y0[e] = 0.5f * y * (1.0f + erff(y * 0.70710678118654752f));
    float z = (x[4 + e] - mu) * rs * g1[e] + b1[e];
    y1[e] = 0.5f * z * (1.0f + erff(z * 0.70710678118654752f));
  }
  float* p = outp + row * 512 + lane * 8;
  *(f32x4*)p = y0;
  *(f32x4*)(p + 4) = y1;
}

// ---------------------------------------------------------------------------
// Host launcher.  Inputs: [0]=t [1]=h [2]=W [3]=b [4]=adj [5]=gamma [6]=beta
// Workspace (~129 MB):
//   adj_bf = ws + 0          (262144 u16)
//   ob     = ws + 16777216   (16.7M u16, bf16 attn out)
//   hp_hi  = ws + 33554432
//   hp_lo  = ws + 50331648
//   Wt_hi  = ws + 67108864   (262144 u16)
//   Wt_lo  = ws + 67371008
// ---------------------------------------------------------------------------
extern "C" void kernel_launch(void* const* d_in, const int* in_sizes, int n_in,
                              void* d_out, int out_size, void* d_ws, size_t ws_size,
                              hipStream_t stream) {
  const float* h     = (const float*)d_in[1];
  const float* W     = (const float*)d_in[2];
  const float* bias  = (const float*)d_in[3];
  const float* adj   = (const float*)d_in[4];
  const float* gamma = (const float*)d_in[5];
  const float* beta  = (const float*)d_in[6];
  float* out = (float*)d_out;

  unsigned short* ws = (unsigned short*)d_ws;
  unsigned short* adj_bf = ws;
  unsigned short* ob     = ws + 16777216;
  unsigned short* hp_hi  = ws + 33554432;
  unsigned short* hp_lo  = ws + 50331648;
  unsigned short* Wt_hi  = ws + 67108864;
  unsigned short* Wt_lo  = ws + 67371008;

  cast_split_Wt<<<1024, 256, 0, stream>>>(W, Wt_hi, Wt_lo);
  cast_adj<<<128, 256, 0, stream>>>(adj, adj_bf);
  proj_gemm<<<1024, 256, 0, stream>>>(h, Wt_hi, Wt_lo, bias, hp_hi, hp_lo);
  attn_kernel<<<1024, 256, 0, stream>>>(hp_hi, hp_lo, adj_bf, ob);
  ln_gelu_kernel<<<8192, 256, 0, stream>>>(ob, out, gamma, beta);
}